// Round 3
// baseline (605.548 us; speedup 1.0000x reference)
//
#include <hip/hip_runtime.h>
#include <hip/hip_bf16.h>

// ---------------- constants ----------------
constexpr int B_ = 8, C_ = 128, Hh = 64, Ww = 64, L_ = Hh * Ww;   // L = 4096
constexpr int CIN_ = 192, K_ = 4, Rr = 8, DFF_ = 512;
constexpr long SZ1 = (long)B_ * C_ * L_;                           // 4,194,304 floats
constexpr float EPSf = 1e-5f;

#define DEVI __device__ __forceinline__

DEVI float sigm(float x) { return 1.f / (1.f + __expf(-x)); }
DEVI float geluf(float x) { return 0.5f * x * (1.f + erff(x * 0.70710678118654752f)); }
DEVI float siluf(float x) { return x * sigm(x); }

// transposed-plane ("scan order") address of position pos in a 64x64 plane
DEVI int tadr(int pos) { return ((pos & 63) << 6) | (pos >> 6); }

// ---------------- generic tiled fp32 GEMM ----------------
template <bool ACC, bool BIAS, bool XGELU, bool SIG, bool SPLIT>
__global__ __launch_bounds__(256) void gemm_k(
    const float* __restrict__ W, const float* __restrict__ X1, long sX1,
    const float* __restrict__ X2, long sX2, int splitRow,
    const float* __restrict__ bias, float* __restrict__ Cp, long sC,
    int M, int N, int K)
{
    __shared__ float sW[32][128];
    __shared__ float sX[32][64];
    const int tid = threadIdx.x;
    const int bn = blockIdx.x, bm = blockIdx.y, bz = blockIdx.z;
    const float* X1b = X1 + (long)bz * sX1;
    const float* X2b = SPLIT ? (X2 + (long)bz * sX2) : nullptr;
    float* Cb = Cp + (long)bz * sC;
    const int n0 = bn * 64, m0 = bm * 128;
    const int tx = tid & 15, ty = tid >> 4;

    float acc[8][4];
#pragma unroll
    for (int i = 0; i < 8; i++)
#pragma unroll
        for (int j = 0; j < 4; j++) acc[i][j] = 0.f;

    const int wrow = tid >> 1;
    const int wk0  = (tid & 1) * 16;
    const int xrow = tid >> 3;
    const int xcol = (tid & 7) * 8;

    for (int k0 = 0; k0 < K; k0 += 32) {
        {
            const float* wp = W + (long)(m0 + wrow) * K + k0 + wk0;
#pragma unroll
            for (int j = 0; j < 4; j++) {
                float4 v = *(const float4*)(wp + j * 4);
                int kk = wk0 + j * 4;
                sW[kk + 0][wrow] = v.x; sW[kk + 1][wrow] = v.y;
                sW[kk + 2][wrow] = v.z; sW[kk + 3][wrow] = v.w;
            }
        }
        {
            const int krow = k0 + xrow;
            const float* xp;
            if (SPLIT && krow >= splitRow)
                xp = X2b + (long)(krow - splitRow) * N + n0 + xcol;
            else
                xp = X1b + (long)krow * N + n0 + xcol;
            float4 a = *(const float4*)xp;
            float4 b = *(const float4*)(xp + 4);
            if (XGELU) {
                a.x = geluf(a.x); a.y = geluf(a.y); a.z = geluf(a.z); a.w = geluf(a.w);
                b.x = geluf(b.x); b.y = geluf(b.y); b.z = geluf(b.z); b.w = geluf(b.w);
            }
            *(float4*)&sX[xrow][xcol] = a;
            *(float4*)&sX[xrow][xcol + 4] = b;
        }
        __syncthreads();
#pragma unroll
        for (int kk = 0; kk < 32; kk++) {
            float4 xv = *(const float4*)&sX[kk][tx << 2];
            float4 wa = *(const float4*)&sW[kk][ty << 3];
            float4 wb = *(const float4*)&sW[kk][(ty << 3) + 4];
            float wv[8] = {wa.x, wa.y, wa.z, wa.w, wb.x, wb.y, wb.z, wb.w};
            float xu[4] = {xv.x, xv.y, xv.z, xv.w};
#pragma unroll
            for (int i = 0; i < 8; i++)
#pragma unroll
                for (int j = 0; j < 4; j++) acc[i][j] += wv[i] * xu[j];
        }
        __syncthreads();
    }

#pragma unroll
    for (int i = 0; i < 8; i++) {
        int m = m0 + (ty << 3) + i;
        float bv = BIAS ? bias[m] : 0.f;
        float* cp = Cb + (long)m * N + n0 + (tx << 2);
        float4 o = make_float4(acc[i][0] + bv, acc[i][1] + bv, acc[i][2] + bv, acc[i][3] + bv);
        if (ACC) {
            float4 p = *(const float4*)cp;
            o.x += p.x; o.y += p.y; o.z += p.z; o.w += p.w;
        }
        if (SIG) { o.x = sigm(o.x); o.y = sigm(o.y); o.z = sigm(o.z); o.w = sigm(o.w); }
        *(float4*)cp = o;
    }
}

// ---------------- channel LayerNorm (channel_first) ----------------
__global__ __launch_bounds__(256) void ln_cf_k(const float* __restrict__ in,
                                               const float* __restrict__ g,
                                               const float* __restrict__ bta,
                                               float* __restrict__ out)
{
    __shared__ float s1[4][64], s2[4][64];
    const int tid = threadIdx.x;
    const int p = tid & 63, q = tid >> 6;
    const long posg = (long)blockIdx.x * 64 + p;
    const int b = (int)(posg / L_);
    const int pp = (int)(posg % L_);
    const float* base = in + ((long)b * C_ + q * 32) * L_ + pp;
    float v[32];
    float s = 0.f, sq = 0.f;
#pragma unroll
    for (int i = 0; i < 32; i++) {
        float t = base[(long)i * L_];
        v[i] = t; s += t; sq += t * t;
    }
    s1[q][p] = s; s2[q][p] = sq;
    __syncthreads();
    float ts = s1[0][p] + s1[1][p] + s1[2][p] + s1[3][p];
    float tq = s2[0][p] + s2[1][p] + s2[2][p] + s2[3][p];
    float mu = ts * (1.f / 128.f);
    float var = tq * (1.f / 128.f) - mu * mu;
    float rs = rsqrtf(var + EPSf);
    float* ob = out + ((long)b * C_ + q * 32) * L_ + pp;
#pragma unroll
    for (int i = 0; i < 32; i++) {
        int c = q * 32 + i;
        ob[(long)i * L_] = (v[i] - mu) * rs * g[c] + bta[c];
    }
}

// ---------------- depthwise 3x3 conv + bias + SiLU ----------------
__global__ __launch_bounds__(256) void dwconv_silu_k(const float* __restrict__ in,
                                                     const float* __restrict__ wts,
                                                     const float* __restrict__ bias,
                                                     float* __restrict__ out)
{
    const long idx = (long)blockIdx.x * 256 + threadIdx.x;
    const int w = (int)(idx & 63);
    const int h = (int)((idx >> 6) & 63);
    const int c = (int)((idx >> 12) & 127);
    const long base = (idx >> 12) << 12;
    const float* p = in + base;
    const float* kw = wts + c * 9;
    float acc = 0.f;
#pragma unroll
    for (int dh = -1; dh <= 1; dh++) {
        int hh = h + dh;
        if ((unsigned)hh >= 64u) continue;
#pragma unroll
        for (int dw = -1; dw <= 1; dw++) {
            int ww2 = w + dw;
            if ((unsigned)ww2 >= 64u) continue;
            acc += p[hh * 64 + ww2] * kw[(dh + 1) * 3 + (dw + 1)];
        }
    }
    acc += bias[c];
    out[idx] = siluf(acc);
}

// ---------------- per-plane 64x64 transpose (= or +=) ----------------
template <bool ADD>
__global__ __launch_bounds__(256) void transp_k(const float* __restrict__ src,
                                                float* __restrict__ dst)
{
    __shared__ float t[64][65];
    const long plane = blockIdx.x;
    const float* s = src + plane * (long)L_;
    float* d = dst + plane * (long)L_;
    const int tid = threadIdx.x;
#pragma unroll
    for (int i = 0; i < 16; i++) {
        int idx = tid + i * 256;
        t[idx >> 6][idx & 63] = s[idx];
    }
    __syncthreads();
#pragma unroll
    for (int i = 0; i < 16; i++) {
        int idx = tid + i * 256;
        int r = idx >> 6, cc = idx & 63;
        float val = t[cc][r];
        if (ADD) d[idx] += val; else d[idx] = val;
    }
}

// ---------------- x_dbl projection (stored in SCAN ORDER) ----------------
__global__ __launch_bounds__(256) void xdbl_k(const float* __restrict__ u,
                                              const float* __restrict__ uT,
                                              const float* __restrict__ xw,
                                              float* __restrict__ out)
{
    __shared__ float wsm[16][132];
    const int k = blockIdx.y, b = blockIdx.z;
    const int tid = threadIdx.x;
#pragma unroll
    for (int i = 0; i < 8; i++) {
        int idx = tid * 8 + i;
        wsm[idx >> 7][idx & 127] = xw[k * 2048 + idx];
    }
    __syncthreads();
    const int dg = (tid & 3) * 4;
    const int lo = tid >> 2;
    const int l = blockIdx.x * 64 + lo;
    const int pos = (k >= 2) ? (L_ - 1 - l) : l;
    const float* usrc = ((k & 1) ? uT : u) + (long)b * C_ * L_ + pos;
    float a0 = 0.f, a1 = 0.f, a2 = 0.f, a3 = 0.f;
#pragma unroll 4
    for (int c = 0; c < C_; c++) {
        float uc = usrc[(long)c * L_];
        a0 += wsm[dg + 0][c] * uc;
        a1 += wsm[dg + 1][c] * uc;
        a2 += wsm[dg + 2][c] * uc;
        a3 += wsm[dg + 3][c] * uc;
    }
    float4 o = make_float4(a0, a1, a2, a3);
    const long s = tadr(l);
    *(float4*)(out + (((long)(b * K_ + k) * L_ + s) << 4) + dg) = o;
}

// ---------------- fused scan: chain = one wave; chunk = lane ----------------
// pass1: per-chunk (P,S) with delta kept in VGPRs; in-wave shfl scan; pass2 replay.
// STORE: k in {0,1}, '=' stores.  !STORE: k in {2,3}, '+=' stores.
template <bool STORE>
__global__ __launch_bounds__(256) void scan_fused_k(const float* __restrict__ xdbl,
                                                    const float* __restrict__ u,
                                                    const float* __restrict__ uT,
                                                    const float* __restrict__ dtw,
                                                    const float* __restrict__ dtb,
                                                    const float* __restrict__ alogs,
                                                    const float* __restrict__ Dsp,
                                                    float* __restrict__ Y0,
                                                    float* __restrict__ Yt)
{
    const int wid = threadIdx.x >> 6;
    const int j   = threadIdx.x & 63;                 // lane = chunk index
    const long cidx = (long)blockIdx.x * 4 + wid;     // 0..2047
    const int c  = (int)(cidx & 127);
    const int kh = (int)((cidx >> 7) & 1);
    const int b  = (int)(cidx >> 8);
    const int k  = STORE ? kh : (kh + 2);
    const bool rev = (k >= 2);
    const float4* xd = (const float4*)(xdbl + (((long)(b * K_ + k) * L_) << 4));
    const float* usrc = ((k & 1) ? u : uT) + ((long)b * C_ + c) * L_;
    float* ydst = ((k & 1) ? Yt : Y0) + ((long)b * C_ + c) * L_;

    float dw[8];
#pragma unroll
    for (int r = 0; r < 8; r++) dw[r] = dtw[((k * C_ + c) << 3) + r];
    const float db = dtb[k * C_ + c];
    float An[4];
#pragma unroll
    for (int n = 0; n < 4; n++) An[n] = -__expf(alogs[((k * C_ + c) << 2) + n]);
    const float Dc = Dsp[k * C_ + c];

    float dreg[64];
    float P0 = 1.f, P1 = 1.f, P2 = 1.f, P3 = 1.f;
    float S0 = 0.f, S1 = 0.f, S2 = 0.f, S3 = 0.f;

    // ---- pass 1: local chunk scan from zero state ----
#pragma unroll
    for (int i = 0; i < 64; i++) {
        const int sidx = (i << 6) | j;
        const int l = (j << 6) | i;
        const int pos = rev ? (L_ - 1 - l) : l;
        float4 d0 = xd[sidx * 4 + 0];
        float4 d1 = xd[sidx * 4 + 1];
        float4 bs = xd[sidx * 4 + 2];
        float uv = usrc[tadr(pos)];
        float z = db + d0.x * dw[0] + d0.y * dw[1] + d0.z * dw[2] + d0.w * dw[3]
                     + d1.x * dw[4] + d1.y * dw[5] + d1.z * dw[6] + d1.w * dw[7];
        float dl = (z > 15.f) ? z : __logf(1.f + __expf(z));
        dreg[i] = dl;
        float du = dl * uv;
        float e;
        e = __expf(dl * An[0]); S0 = e * S0 + du * bs.x; P0 *= e;
        e = __expf(dl * An[1]); S1 = e * S1 + du * bs.y; P1 *= e;
        e = __expf(dl * An[2]); S2 = e * S2 + du * bs.z; P2 *= e;
        e = __expf(dl * An[3]); S3 = e * S3 + du * bs.w; P3 *= e;
    }

    // ---- in-wave inclusive scan over chunk (P,S) pairs ----
#pragma unroll
    for (int d = 1; d < 64; d <<= 1) {
        float pu0 = __shfl_up(P0, d, 64), pu1 = __shfl_up(P1, d, 64);
        float pu2 = __shfl_up(P2, d, 64), pu3 = __shfl_up(P3, d, 64);
        float su0 = __shfl_up(S0, d, 64), su1 = __shfl_up(S1, d, 64);
        float su2 = __shfl_up(S2, d, 64), su3 = __shfl_up(S3, d, 64);
        if (j >= d) {
            S0 += P0 * su0; S1 += P1 * su1; S2 += P2 * su2; S3 += P3 * su3;
            P0 *= pu0; P1 *= pu1; P2 *= pu2; P3 *= pu3;
        }
    }
    // entering state for chunk j = inclusive result of chunk j-1
    float h0 = __shfl_up(S0, 1, 64), h1 = __shfl_up(S1, 1, 64);
    float h2 = __shfl_up(S2, 1, 64), h3 = __shfl_up(S3, 1, 64);
    if (j == 0) { h0 = 0.f; h1 = 0.f; h2 = 0.f; h3 = 0.f; }

    // ---- pass 2: replay with true entering state, emit y ----
#pragma unroll
    for (int i = 0; i < 64; i++) {
        const int sidx = (i << 6) | j;
        const int l = (j << 6) | i;
        const int pos = rev ? (L_ - 1 - l) : l;
        const int ta = tadr(pos);
        float4 bs = xd[sidx * 4 + 2];
        float4 cs = xd[sidx * 4 + 3];
        float uv = usrc[ta];
        float dl = dreg[i];
        float du = dl * uv;
        float e;
        e = __expf(dl * An[0]); h0 = e * h0 + du * bs.x;
        e = __expf(dl * An[1]); h1 = e * h1 + du * bs.y;
        e = __expf(dl * An[2]); h2 = e * h2 + du * bs.z;
        e = __expf(dl * An[3]); h3 = e * h3 + du * bs.w;
        float y = h0 * cs.x + h1 * cs.y + h2 * cs.z + h3 * cs.w + Dc * uv;
        if (STORE) ydst[ta] = y; else ydst[ta] += y;
    }
}

// ---------------- final blend: out = g*z + (1-g)*h ----------------
__global__ __launch_bounds__(256) void final_k(const float* __restrict__ g,
                                               const float* __restrict__ z,
                                               const float* __restrict__ h,
                                               float* __restrict__ out)
{
    const long i = ((long)blockIdx.x * 256 + threadIdx.x) * 4;
    float4 gv = *(const float4*)(g + i);
    float4 zv = *(const float4*)(z + i);
    float4 hv = *(const float4*)(h + i);
    float4 o;
    o.x = hv.x + gv.x * (zv.x - hv.x);
    o.y = hv.y + gv.y * (zv.y - hv.y);
    o.z = hv.z + gv.z * (zv.z - hv.z);
    o.w = hv.w + gv.w * (zv.w - hv.w);
    *(float4*)(out + i) = o;
}

// ---------------- launch ----------------
extern "C" void kernel_launch(void* const* d_in, const int* in_sizes, int n_in,
                              void* d_out, int out_size, void* d_ws, size_t ws_size,
                              hipStream_t stream)
{
    const float* h_in      = (const float*)d_in[0];
    const float* x_in      = (const float*)d_in[4];
    const float* in_proj_w = (const float*)d_in[5];
    const float* in_proj_b = (const float*)d_in[6];
    const float* ln1_g     = (const float*)d_in[7];
    const float* ln1_b     = (const float*)d_in[8];
    const float* ssm_in_w  = (const float*)d_in[9];
    const float* conv_w    = (const float*)d_in[10];
    const float* conv_b    = (const float*)d_in[11];
    const float* x_proj_w  = (const float*)d_in[12];
    const float* dt_w      = (const float*)d_in[13];
    const float* dt_b      = (const float*)d_in[14];
    const float* A_logs    = (const float*)d_in[15];
    const float* Dsp       = (const float*)d_in[16];
    const float* outnorm_g = (const float*)d_in[17];
    const float* outnorm_b = (const float*)d_in[18];
    const float* out_proj_w= (const float*)d_in[19];
    const float* ln2_g     = (const float*)d_in[20];
    const float* ln2_b     = (const float*)d_in[21];
    const float* fc1_w     = (const float*)d_in[22];
    const float* fc1_b     = (const float*)d_in[23];
    const float* fc2_w     = (const float*)d_in[24];
    const float* fc2_b     = (const float*)d_in[25];
    const float* gate_w    = (const float*)d_in[26];
    const float* gate_b    = (const float*)d_in[27];

    float* ws   = (float*)d_ws;
    float* fz   = ws;              // feat -> z (in place)
    float* ubuf = ws + SZ1;        // u ; MLP hidden overlays
    float* tbuf = ws + 2 * SZ1;    // u0 -> u_T -> y_norm
    float* ybuf = ws + 3 * SZ1;    // ln1out -> TY0 -> ln2out
    float* xdbl = ws + 4 * SZ1;    // [B,K,L(scan order),16]
    float* mbuf = ubuf;
    float* gbuf = (float*)d_out;   // TYt -> merged y -> gate -> final out

    const dim3 blk(256);
    const long sBC = (long)C_ * L_;
    const long sX  = (long)CIN_ * L_;
    const long sM  = (long)DFF_ * L_;

    // 1) feat = in_proj @ concat(h, x) + b
    gemm_k<false, true, false, false, true><<<dim3(64, 1, 8), blk, 0, stream>>>(
        in_proj_w, h_in, sBC, x_in, sX, 128, in_proj_b, fz, sBC, 128, L_, 320);
    // 2) ln1(feat) -> ybuf
    ln_cf_k<<<dim3(512), blk, 0, stream>>>(fz, ln1_g, ln1_b, ybuf);
    // 3) u0 = ssm_in @ ln1 -> tbuf
    gemm_k<false, false, false, false, false><<<dim3(64, 1, 8), blk, 0, stream>>>(
        ssm_in_w, ybuf, sBC, nullptr, 0, 1 << 30, nullptr, tbuf, sBC, 128, L_, 128);
    // 4) u = silu(dwconv(u0) + conv_b) -> ubuf
    dwconv_silu_k<<<dim3(16384), blk, 0, stream>>>(tbuf, conv_w, conv_b, ubuf);
    // 5) u_T -> tbuf
    transp_k<false><<<dim3(1024), blk, 0, stream>>>(ubuf, tbuf);
    // 6) x_dbl (scan-order layout)
    xdbl_k<<<dim3(64, 4, 8), blk, 0, stream>>>(ubuf, tbuf, x_proj_w, xdbl);
    // 7) fused scan k={0,1}: TY0 '=' -> ybuf, TYt '=' -> gbuf
    scan_fused_k<true><<<dim3(512), blk, 0, stream>>>(xdbl, ubuf, tbuf, dt_w, dt_b,
                                                      A_logs, Dsp, ybuf, gbuf);
    // 8) fused scan k={2,3}: '+='
    scan_fused_k<false><<<dim3(512), blk, 0, stream>>>(xdbl, ubuf, tbuf, dt_w, dt_b,
                                                       A_logs, Dsp, ybuf, gbuf);
    // 9) merged y: gbuf += transpose(ybuf)
    transp_k<true><<<dim3(1024), blk, 0, stream>>>(ybuf, gbuf);
    // 10) outnorm(y) -> tbuf
    ln_cf_k<<<dim3(512), blk, 0, stream>>>(gbuf, outnorm_g, outnorm_b, tbuf);
    // 11) z = feat + out_proj @ y_norm   (ACC into fz)
    gemm_k<true, false, false, false, false><<<dim3(64, 1, 8), blk, 0, stream>>>(
        out_proj_w, tbuf, sBC, nullptr, 0, 1 << 30, nullptr, fz, sBC, 128, L_, 128);
    // 12) ln2(z) -> ybuf
    ln_cf_k<<<dim3(512), blk, 0, stream>>>(fz, ln2_g, ln2_b, ybuf);
    // 13-16) MLP in two 4-batch halves
    for (int half = 0; half < 2; half++) {
        long o = (long)half * 4 * sBC;
        gemm_k<false, true, false, false, false><<<dim3(64, 4, 4), blk, 0, stream>>>(
            fc1_w, ybuf + o, sBC, nullptr, 0, 1 << 30, fc1_b, mbuf, sM, 512, L_, 128);
        gemm_k<true, true, true, false, false><<<dim3(64, 1, 4), blk, 0, stream>>>(
            fc2_w, mbuf, sM, nullptr, 0, 1 << 30, fc2_b, fz + o, sBC, 128, L_, 512);
    }
    // 17) g = sigmoid(gate @ z + b) -> gbuf
    gemm_k<false, true, false, true, false><<<dim3(64, 1, 8), blk, 0, stream>>>(
        gate_w, fz, sBC, nullptr, 0, 1 << 30, gate_b, gbuf, sBC, 128, L_, 128);
    // 18) out = g*z + (1-g)*h
    final_k<<<dim3(4096), blk, 0, stream>>>(gbuf, fz, h_in, (float*)d_out);
}

// Round 4
// 397.489 us; speedup vs baseline: 1.5234x; 1.5234x over previous
//
#include <hip/hip_runtime.h>
#include <hip/hip_bf16.h>

// ---------------- constants ----------------
constexpr int B_ = 8, C_ = 128, Hh = 64, Ww = 64, L_ = Hh * Ww;   // L = 4096
constexpr int CIN_ = 192, K_ = 4, Rr = 8, DFF_ = 512;
constexpr long SZ1 = (long)B_ * C_ * L_;                           // 4,194,304 floats
constexpr int CH_ = 64, NCH_ = L_ / CH_;
constexpr float EPSf = 1e-5f;

#define DEVI __device__ __forceinline__

using s16x4 = __attribute__((ext_vector_type(4))) short;
using s16x8 = __attribute__((ext_vector_type(8))) short;
using f32x4 = __attribute__((ext_vector_type(4))) float;

DEVI float sigm(float x) { return 1.f / (1.f + __expf(-x)); }
DEVI float geluf(float x) { return 0.5f * x * (1.f + erff(x * 0.70710678118654752f)); }
DEVI float siluf(float x) { return x * sigm(x); }
DEVI float softp(float z) { return (z > 15.f) ? z : __logf(1.f + __expf(z)); }

// float -> bf16 bits, round-to-nearest-even
DEVI unsigned short f2bf(float f) {
    unsigned u = __float_as_uint(f);
    u += 0x7fffu + ((u >> 16) & 1u);
    return (unsigned short)(u >> 16);
}

// transposed-plane ("scan order") address of position pos in a 64x64 plane
DEVI int tadr(int pos) { return ((pos & 63) << 6) | (pos >> 6); }

// ---------------- bf16 MFMA tiled GEMM ----------------
// C[M,N] (+)= W[M,K] @ X[K,N] (+bias) (sigmoid) ; X split (concat) / gelu on load.
// block = 256 thr = 4 waves; tile 128x128; BK=32; fp32->bf16 conversion in staging.
template <bool ACC, bool BIAS, bool XGELU, bool SIG, bool SPLIT>
__global__ __launch_bounds__(256) void gemm_k(
    const float* __restrict__ W, const float* __restrict__ X1, long sX1,
    const float* __restrict__ X2, long sX2, int splitRow,
    const float* __restrict__ bias, float* __restrict__ Cp, long sC,
    int M, int N, int K)
{
    __shared__ unsigned short sA[128][40];   // [m][k] bf16, +8 pad
    __shared__ unsigned short sB[128][40];   // [n][k] bf16, +8 pad
    const int tid = threadIdx.x;
    const int bn = blockIdx.x, bm = blockIdx.y, bz = blockIdx.z;
    const float* X1b = X1 + (long)bz * sX1;
    const float* X2b = SPLIT ? (X2 + (long)bz * sX2) : nullptr;
    float* Cb = Cp + (long)bz * sC;
    const int n0 = bn * 128, m0 = bm * 128;

    const int l = tid & 63, w = tid >> 6;
    const int wm = w >> 1, wn = w & 1;             // 2x2 wave grid
    const int lr = l & 15, lk = (l >> 4) * 8;

    // A staging: 2 thr/row, 16 k each
    const int awrow = tid >> 1, awk = (tid & 1) * 16;
    // B staging: 4x4 micro-transpose; nb in 0..31, kb in 0..7
    const int bnb = tid & 31, bkb = tid >> 5;

    f32x4 acc[4][4];
#pragma unroll
    for (int i = 0; i < 4; i++)
#pragma unroll
        for (int j = 0; j < 4; j++) acc[i][j] = (f32x4)0.f;

    for (int k0 = 0; k0 < K; k0 += 32) {
        // ---- stage A (W tile) ----
        {
            const float* wp = W + (long)(m0 + awrow) * K + k0 + awk;
            float4 f0 = *(const float4*)(wp + 0);
            float4 f1 = *(const float4*)(wp + 4);
            float4 f2 = *(const float4*)(wp + 8);
            float4 f3 = *(const float4*)(wp + 12);
            s16x8 v0, v1;
            v0[0]=f2bf(f0.x); v0[1]=f2bf(f0.y); v0[2]=f2bf(f0.z); v0[3]=f2bf(f0.w);
            v0[4]=f2bf(f1.x); v0[5]=f2bf(f1.y); v0[6]=f2bf(f1.z); v0[7]=f2bf(f1.w);
            v1[0]=f2bf(f2.x); v1[1]=f2bf(f2.y); v1[2]=f2bf(f2.z); v1[3]=f2bf(f2.w);
            v1[4]=f2bf(f3.x); v1[5]=f2bf(f3.y); v1[6]=f2bf(f3.z); v1[7]=f2bf(f3.w);
            *(s16x8*)&sA[awrow][awk] = v0;
            *(s16x8*)&sA[awrow][awk + 8] = v1;
        }
        // ---- stage B (X tile, transposed to [n][k]) ----
        {
            const int krow = k0 + bkb * 4;
            const float* xp;
            if (SPLIT && krow >= splitRow)
                xp = X2b + (long)(krow - splitRow) * N + n0 + bnb * 4;
            else
                xp = X1b + (long)krow * N + n0 + bnb * 4;
            float4 r0 = *(const float4*)(xp + 0 * (long)N);
            float4 r1 = *(const float4*)(xp + 1 * (long)N);
            float4 r2 = *(const float4*)(xp + 2 * (long)N);
            float4 r3 = *(const float4*)(xp + 3 * (long)N);
            if (XGELU) {
                r0.x=geluf(r0.x); r0.y=geluf(r0.y); r0.z=geluf(r0.z); r0.w=geluf(r0.w);
                r1.x=geluf(r1.x); r1.y=geluf(r1.y); r1.z=geluf(r1.z); r1.w=geluf(r1.w);
                r2.x=geluf(r2.x); r2.y=geluf(r2.y); r2.z=geluf(r2.z); r2.w=geluf(r2.w);
                r3.x=geluf(r3.x); r3.y=geluf(r3.y); r3.z=geluf(r3.z); r3.w=geluf(r3.w);
            }
            const float* p0 = (const float*)&r0;
            const float* p1 = (const float*)&r1;
            const float* p2 = (const float*)&r2;
            const float* p3 = (const float*)&r3;
#pragma unroll
            for (int c = 0; c < 4; c++) {
                s16x4 v;
                v[0] = f2bf(p0[c]); v[1] = f2bf(p1[c]);
                v[2] = f2bf(p2[c]); v[3] = f2bf(p3[c]);
                *(s16x4*)&sB[bnb * 4 + c][bkb * 4] = v;
            }
        }
        __syncthreads();
        // ---- MFMA ----
        s16x8 af[4], bf[4];
#pragma unroll
        for (int mi = 0; mi < 4; mi++) af[mi] = *(const s16x8*)&sA[wm * 64 + mi * 16 + lr][lk];
#pragma unroll
        for (int ni = 0; ni < 4; ni++) bf[ni] = *(const s16x8*)&sB[wn * 64 + ni * 16 + lr][lk];
#pragma unroll
        for (int mi = 0; mi < 4; mi++)
#pragma unroll
            for (int ni = 0; ni < 4; ni++)
                acc[mi][ni] = __builtin_amdgcn_mfma_f32_16x16x32_bf16(af[mi], bf[ni], acc[mi][ni], 0, 0, 0);
        __syncthreads();
    }

    // ---- epilogue: D row = (l>>4)*4 + r, col = l&15 (verified layout) ----
#pragma unroll
    for (int mi = 0; mi < 4; mi++) {
#pragma unroll
        for (int r = 0; r < 4; r++) {
            const int row = m0 + wm * 64 + mi * 16 + (l >> 4) * 4 + r;
            const float bv = BIAS ? bias[row] : 0.f;
            float* rp = Cb + (long)row * N + n0 + wn * 64 + lr;
#pragma unroll
            for (int ni = 0; ni < 4; ni++) {
                float v = acc[mi][ni][r] + bv;
                float* cp = rp + ni * 16;
                if (ACC) v += *cp;
                if (SIG) v = sigm(v);
                *cp = v;
            }
        }
    }
}

// ---------------- channel LayerNorm (channel_first) ----------------
__global__ __launch_bounds__(256) void ln_cf_k(const float* __restrict__ in,
                                               const float* __restrict__ g,
                                               const float* __restrict__ bta,
                                               float* __restrict__ out)
{
    __shared__ float s1[4][64], s2[4][64];
    const int tid = threadIdx.x;
    const int p = tid & 63, q = tid >> 6;
    const long posg = (long)blockIdx.x * 64 + p;
    const int b = (int)(posg / L_);
    const int pp = (int)(posg % L_);
    const float* base = in + ((long)b * C_ + q * 32) * L_ + pp;
    float v[32];
    float s = 0.f, sq = 0.f;
#pragma unroll
    for (int i = 0; i < 32; i++) {
        float t = base[(long)i * L_];
        v[i] = t; s += t; sq += t * t;
    }
    s1[q][p] = s; s2[q][p] = sq;
    __syncthreads();
    float ts = s1[0][p] + s1[1][p] + s1[2][p] + s1[3][p];
    float tq = s2[0][p] + s2[1][p] + s2[2][p] + s2[3][p];
    float mu = ts * (1.f / 128.f);
    float var = tq * (1.f / 128.f) - mu * mu;
    float rs = rsqrtf(var + EPSf);
    float* ob = out + ((long)b * C_ + q * 32) * L_ + pp;
#pragma unroll
    for (int i = 0; i < 32; i++) {
        int c = q * 32 + i;
        ob[(long)i * L_] = (v[i] - mu) * rs * g[c] + bta[c];
    }
}

// ---------------- depthwise 3x3 conv + bias + SiLU ----------------
__global__ __launch_bounds__(256) void dwconv_silu_k(const float* __restrict__ in,
                                                     const float* __restrict__ wts,
                                                     const float* __restrict__ bias,
                                                     float* __restrict__ out)
{
    const long idx = (long)blockIdx.x * 256 + threadIdx.x;
    const int w = (int)(idx & 63);
    const int h = (int)((idx >> 6) & 63);
    const int c = (int)((idx >> 12) & 127);
    const long base = (idx >> 12) << 12;
    const float* p = in + base;
    const float* kw = wts + c * 9;
    float acc = 0.f;
#pragma unroll
    for (int dh = -1; dh <= 1; dh++) {
        int hh = h + dh;
        if ((unsigned)hh >= 64u) continue;
#pragma unroll
        for (int dw = -1; dw <= 1; dw++) {
            int ww2 = w + dw;
            if ((unsigned)ww2 >= 64u) continue;
            acc += p[hh * 64 + ww2] * kw[(dh + 1) * 3 + (dw + 1)];
        }
    }
    acc += bias[c];
    out[idx] = siluf(acc);
}

// ---------------- per-plane 64x64 transpose (= or +=) ----------------
template <bool ADD>
__global__ __launch_bounds__(256) void transp_k(const float* __restrict__ src,
                                                float* __restrict__ dst)
{
    __shared__ float t[64][65];
    const long plane = blockIdx.x;
    const float* s = src + plane * (long)L_;
    float* d = dst + plane * (long)L_;
    const int tid = threadIdx.x;
#pragma unroll
    for (int i = 0; i < 16; i++) {
        int idx = tid + i * 256;
        t[idx >> 6][idx & 63] = s[idx];
    }
    __syncthreads();
#pragma unroll
    for (int i = 0; i < 16; i++) {
        int idx = tid + i * 256;
        int r = idx >> 6, cc = idx & 63;
        float val = t[cc][r];
        if (ADD) d[idx] += val; else d[idx] = val;
    }
}

// ---------------- x_dbl projection (stored in SCAN ORDER) ----------------
__global__ __launch_bounds__(256) void xdbl_k(const float* __restrict__ u,
                                              const float* __restrict__ uT,
                                              const float* __restrict__ xw,
                                              float* __restrict__ out)
{
    __shared__ float wsm[16][132];
    const int k = blockIdx.y, b = blockIdx.z;
    const int tid = threadIdx.x;
#pragma unroll
    for (int i = 0; i < 8; i++) {
        int idx = tid * 8 + i;
        wsm[idx >> 7][idx & 127] = xw[k * 2048 + idx];
    }
    __syncthreads();
    const int dg = (tid & 3) * 4;
    const int lo = tid >> 2;
    const int l = blockIdx.x * 64 + lo;
    const int pos = (k >= 2) ? (L_ - 1 - l) : l;
    const float* usrc = ((k & 1) ? uT : u) + (long)b * C_ * L_ + pos;
    float a0 = 0.f, a1 = 0.f, a2 = 0.f, a3 = 0.f;
#pragma unroll 4
    for (int c = 0; c < C_; c++) {
        float uc = usrc[(long)c * L_];
        a0 += wsm[dg + 0][c] * uc;
        a1 += wsm[dg + 1][c] * uc;
        a2 += wsm[dg + 2][c] * uc;
        a3 += wsm[dg + 3][c] * uc;
    }
    float4 o = make_float4(a0, a1, a2, a3);
    const long s = tadr(l);
    *(float4*)(out + (((long)(b * K_ + k) * L_ + s) << 4) + dg) = o;
}

// ---------------- scan phase 1 (fast math) ----------------
__global__ __launch_bounds__(256) void scan_ph1_k(const float* __restrict__ xdbl,
                                                  const float* __restrict__ u,
                                                  const float* __restrict__ uT,
                                                  const float* __restrict__ dtw,
                                                  const float* __restrict__ dtb,
                                                  const float* __restrict__ alogs,
                                                  float* __restrict__ st)
{
    const long t = (long)blockIdx.x * 256 + threadIdx.x;
    const int j = (int)(t & 63);
    const long chain = t >> 6;
    const int c = (int)(chain & 127);
    const int bk = (int)(chain >> 7);
    const int k = bk & 3, b = bk >> 2;
    const float4* xd = (const float4*)(xdbl + (((long)(b * K_ + k) * L_) << 4));
    const float* usrc = ((k & 1) ? u : uT) + ((long)b * C_ + c) * L_;
    const bool rev = (k >= 2);
    float dw[8];
#pragma unroll
    for (int r = 0; r < 8; r++) dw[r] = dtw[((k * C_ + c) << 3) + r];
    const float db = dtb[k * C_ + c];
    float An[4];
#pragma unroll
    for (int n = 0; n < 4; n++) An[n] = -__expf(alogs[((k * C_ + c) << 2) + n]);
    float P0 = 1.f, P1 = 1.f, P2 = 1.f, P3 = 1.f;
    float S0 = 0.f, S1 = 0.f, S2 = 0.f, S3 = 0.f;
    for (int i = 0; i < CH_; i++) {
        int sidx = (i << 6) | j;
        int l = (j << 6) | i;
        int pos = rev ? (L_ - 1 - l) : l;
        float4 d0 = xd[sidx * 4 + 0];
        float4 d1 = xd[sidx * 4 + 1];
        float4 bs = xd[sidx * 4 + 2];
        float uv = usrc[tadr(pos)];
        float z = db + d0.x * dw[0] + d0.y * dw[1] + d0.z * dw[2] + d0.w * dw[3]
                     + d1.x * dw[4] + d1.y * dw[5] + d1.z * dw[6] + d1.w * dw[7];
        float dl = softp(z);
        float du = dl * uv;
        float e;
        e = __expf(dl * An[0]); S0 = e * S0 + du * bs.x; P0 *= e;
        e = __expf(dl * An[1]); S1 = e * S1 + du * bs.y; P1 *= e;
        e = __expf(dl * An[2]); S2 = e * S2 + du * bs.z; P2 *= e;
        e = __expf(dl * An[3]); S3 = e * S3 + du * bs.w; P3 *= e;
    }
    float* o = st + (chain << 9) + (j << 3);
    *(float4*)o = make_float4(P0, P1, P2, P3);
    *(float4*)(o + 4) = make_float4(S0, S1, S2, S3);
}

// ---------------- scan mid: wave-parallel scan over 64 chunk-(P,S) pairs ----------------
__global__ __launch_bounds__(256) void scan_mid_k(float* __restrict__ st)
{
    const long chain = ((long)blockIdx.x * 256 + threadIdx.x) >> 6;
    const int lane = threadIdx.x & 63;
    float* base = st + (chain << 9) + (lane << 3);
    float4 P = *(float4*)base;
    float4 S = *(float4*)(base + 4);
#pragma unroll
    for (int d = 1; d < 64; d <<= 1) {
        float4 Pu, Su;
        Pu.x = __shfl_up(P.x, d, 64); Pu.y = __shfl_up(P.y, d, 64);
        Pu.z = __shfl_up(P.z, d, 64); Pu.w = __shfl_up(P.w, d, 64);
        Su.x = __shfl_up(S.x, d, 64); Su.y = __shfl_up(S.y, d, 64);
        Su.z = __shfl_up(S.z, d, 64); Su.w = __shfl_up(S.w, d, 64);
        if (lane >= d) {
            S.x += P.x * Su.x; S.y += P.y * Su.y;
            S.z += P.z * Su.z; S.w += P.w * Su.w;
            P.x *= Pu.x; P.y *= Pu.y; P.z *= Pu.z; P.w *= Pu.w;
        }
    }
    float4 E;
    E.x = __shfl_up(S.x, 1, 64); E.y = __shfl_up(S.y, 1, 64);
    E.z = __shfl_up(S.z, 1, 64); E.w = __shfl_up(S.w, 1, 64);
    if (lane == 0) { E.x = 0.f; E.y = 0.f; E.z = 0.f; E.w = 0.f; }
    *(float4*)(base + 4) = E;
}

// ---------------- scan phase 2 (fast math) ----------------
template <bool STORE>
__global__ __launch_bounds__(256) void scan_ph2_k(const float* __restrict__ xdbl,
                                                  const float* __restrict__ u,
                                                  const float* __restrict__ uT,
                                                  const float* __restrict__ dtw,
                                                  const float* __restrict__ dtb,
                                                  const float* __restrict__ alogs,
                                                  const float* __restrict__ Dsp,
                                                  const float* __restrict__ st,
                                                  float* __restrict__ Y0,
                                                  float* __restrict__ Yt)
{
    const int k = STORE ? blockIdx.y : (blockIdx.y + 2);
    const long t = (long)blockIdx.x * 256 + threadIdx.x;
    const int j = (int)(t & 63);
    const long bc = t >> 6;
    const int c = (int)(bc & 127);
    const int b = (int)(bc >> 7);
    const long chain = (long)(b * K_ + k) * C_ + c;
    const float4* xd = (const float4*)(xdbl + (((long)(b * K_ + k) * L_) << 4));
    const float* usrc = ((k & 1) ? u : uT) + ((long)b * C_ + c) * L_;
    float* ydst = ((k & 1) ? Yt : Y0) + ((long)b * C_ + c) * L_;
    const bool rev = (k >= 2);
    float dw[8];
#pragma unroll
    for (int r = 0; r < 8; r++) dw[r] = dtw[((k * C_ + c) << 3) + r];
    const float db = dtb[k * C_ + c];
    float An[4];
#pragma unroll
    for (int n = 0; n < 4; n++) An[n] = -__expf(alogs[((k * C_ + c) << 2) + n]);
    const float Dc = Dsp[k * C_ + c];
    float4 H = *(const float4*)(st + (chain << 9) + (j << 3) + 4);
    float h0 = H.x, h1 = H.y, h2 = H.z, h3 = H.w;
    for (int i = 0; i < CH_; i++) {
        int sidx = (i << 6) | j;
        int l = (j << 6) | i;
        int pos = rev ? (L_ - 1 - l) : l;
        int ta = tadr(pos);
        float4 d0 = xd[sidx * 4 + 0];
        float4 d1 = xd[sidx * 4 + 1];
        float4 bs = xd[sidx * 4 + 2];
        float4 cs = xd[sidx * 4 + 3];
        float uv = usrc[ta];
        float z = db + d0.x * dw[0] + d0.y * dw[1] + d0.z * dw[2] + d0.w * dw[3]
                     + d1.x * dw[4] + d1.y * dw[5] + d1.z * dw[6] + d1.w * dw[7];
        float dl = softp(z);
        float du = dl * uv;
        float e;
        e = __expf(dl * An[0]); h0 = e * h0 + du * bs.x;
        e = __expf(dl * An[1]); h1 = e * h1 + du * bs.y;
        e = __expf(dl * An[2]); h2 = e * h2 + du * bs.z;
        e = __expf(dl * An[3]); h3 = e * h3 + du * bs.w;
        float y = h0 * cs.x + h1 * cs.y + h2 * cs.z + h3 * cs.w + Dc * uv;
        if (STORE) ydst[ta] = y; else ydst[ta] += y;
    }
}

// ---------------- final blend: out = g*z + (1-g)*h ----------------
__global__ __launch_bounds__(256) void final_k(const float* __restrict__ g,
                                               const float* __restrict__ z,
                                               const float* __restrict__ h,
                                               float* __restrict__ out)
{
    const long i = ((long)blockIdx.x * 256 + threadIdx.x) * 4;
    float4 gv = *(const float4*)(g + i);
    float4 zv = *(const float4*)(z + i);
    float4 hv = *(const float4*)(h + i);
    float4 o;
    o.x = hv.x + gv.x * (zv.x - hv.x);
    o.y = hv.y + gv.y * (zv.y - hv.y);
    o.z = hv.z + gv.z * (zv.z - hv.z);
    o.w = hv.w + gv.w * (zv.w - hv.w);
    *(float4*)(out + i) = o;
}

// ---------------- launch ----------------
extern "C" void kernel_launch(void* const* d_in, const int* in_sizes, int n_in,
                              void* d_out, int out_size, void* d_ws, size_t ws_size,
                              hipStream_t stream)
{
    const float* h_in      = (const float*)d_in[0];
    const float* x_in      = (const float*)d_in[4];
    const float* in_proj_w = (const float*)d_in[5];
    const float* in_proj_b = (const float*)d_in[6];
    const float* ln1_g     = (const float*)d_in[7];
    const float* ln1_b     = (const float*)d_in[8];
    const float* ssm_in_w  = (const float*)d_in[9];
    const float* conv_w    = (const float*)d_in[10];
    const float* conv_b    = (const float*)d_in[11];
    const float* x_proj_w  = (const float*)d_in[12];
    const float* dt_w      = (const float*)d_in[13];
    const float* dt_b      = (const float*)d_in[14];
    const float* A_logs    = (const float*)d_in[15];
    const float* Dsp       = (const float*)d_in[16];
    const float* outnorm_g = (const float*)d_in[17];
    const float* outnorm_b = (const float*)d_in[18];
    const float* out_proj_w= (const float*)d_in[19];
    const float* ln2_g     = (const float*)d_in[20];
    const float* ln2_b     = (const float*)d_in[21];
    const float* fc1_w     = (const float*)d_in[22];
    const float* fc1_b     = (const float*)d_in[23];
    const float* fc2_w     = (const float*)d_in[24];
    const float* fc2_b     = (const float*)d_in[25];
    const float* gate_w    = (const float*)d_in[26];
    const float* gate_b    = (const float*)d_in[27];

    float* ws   = (float*)d_ws;
    float* fz   = ws;              // feat -> z (in place)
    float* ubuf = ws + SZ1;        // u ; MLP hidden overlays
    float* tbuf = ws + 2 * SZ1;    // u0 -> u_T -> y_norm
    float* ybuf = ws + 3 * SZ1;    // ln1out -> TY0 -> ln2out
    float* xdbl = ws + 4 * SZ1;    // [B,K,L(scan order),16]
    float* stbf = ws + 4 * SZ1 + 2097152;
    float* mbuf = ubuf;
    float* gbuf = (float*)d_out;   // TYt -> merged y -> gate -> final out

    const dim3 blk(256);
    const long sBC = (long)C_ * L_;
    const long sX  = (long)CIN_ * L_;
    const long sM  = (long)DFF_ * L_;

    // 1) feat = in_proj @ concat(h, x) + b
    gemm_k<false, true, false, false, true><<<dim3(32, 1, 8), blk, 0, stream>>>(
        in_proj_w, h_in, sBC, x_in, sX, 128, in_proj_b, fz, sBC, 128, L_, 320);
    // 2) ln1(feat) -> ybuf
    ln_cf_k<<<dim3(512), blk, 0, stream>>>(fz, ln1_g, ln1_b, ybuf);
    // 3) u0 = ssm_in @ ln1 -> tbuf
    gemm_k<false, false, false, false, false><<<dim3(32, 1, 8), blk, 0, stream>>>(
        ssm_in_w, ybuf, sBC, nullptr, 0, 1 << 30, nullptr, tbuf, sBC, 128, L_, 128);
    // 4) u = silu(dwconv(u0) + conv_b) -> ubuf
    dwconv_silu_k<<<dim3(16384), blk, 0, stream>>>(tbuf, conv_w, conv_b, ubuf);
    // 5) u_T -> tbuf
    transp_k<false><<<dim3(1024), blk, 0, stream>>>(ubuf, tbuf);
    // 6) x_dbl (scan-order layout)
    xdbl_k<<<dim3(64, 4, 8), blk, 0, stream>>>(ubuf, tbuf, x_proj_w, xdbl);
    // 7) scan phase 1
    scan_ph1_k<<<dim3(1024), blk, 0, stream>>>(xdbl, ubuf, tbuf, dt_w, dt_b, A_logs, stbf);
    // 8) chunk-boundary chaining (wave-parallel)
    scan_mid_k<<<dim3(1024), blk, 0, stream>>>(stbf);
    // 9) scan phase 2, k=0 -> TY0 '=', k=1 -> TYt '='
    scan_ph2_k<true><<<dim3(256, 2), blk, 0, stream>>>(xdbl, ubuf, tbuf, dt_w, dt_b,
                                                       A_logs, Dsp, stbf, ybuf, gbuf);
    // 10) scan phase 2, k=2 -> TY0 '+=', k=3 -> TYt '+='
    scan_ph2_k<false><<<dim3(256, 2), blk, 0, stream>>>(xdbl, ubuf, tbuf, dt_w, dt_b,
                                                        A_logs, Dsp, stbf, ybuf, gbuf);
    // 11) merged y: gbuf += transpose(ybuf)
    transp_k<true><<<dim3(1024), blk, 0, stream>>>(ybuf, gbuf);
    // 12) outnorm(y) -> tbuf
    ln_cf_k<<<dim3(512), blk, 0, stream>>>(gbuf, outnorm_g, outnorm_b, tbuf);
    // 13) z = feat + out_proj @ y_norm   (ACC into fz)
    gemm_k<true, false, false, false, false><<<dim3(32, 1, 8), blk, 0, stream>>>(
        out_proj_w, tbuf, sBC, nullptr, 0, 1 << 30, nullptr, fz, sBC, 128, L_, 128);
    // 14) ln2(z) -> ybuf
    ln_cf_k<<<dim3(512), blk, 0, stream>>>(fz, ln2_g, ln2_b, ybuf);
    // 15-18) MLP in two 4-batch halves
    for (int half = 0; half < 2; half++) {
        long o = (long)half * 4 * sBC;
        gemm_k<false, true, false, false, false><<<dim3(32, 4, 4), blk, 0, stream>>>(
            fc1_w, ybuf + o, sBC, nullptr, 0, 1 << 30, fc1_b, mbuf, sM, 512, L_, 128);
        gemm_k<true, true, true, false, false><<<dim3(32, 1, 4), blk, 0, stream>>>(
            fc2_w, mbuf, sM, nullptr, 0, 1 << 30, fc2_b, fz + o, sBC, 128, L_, 512);
    }
    // 19) g = sigmoid(gate @ z + b) -> gbuf
    gemm_k<false, true, false, true, false><<<dim3(32, 1, 8), blk, 0, stream>>>(
        gate_w, fz, sBC, nullptr, 0, 1 << 30, gate_b, gbuf, sBC, 128, L_, 128);
    // 20) out = g*z + (1-g)*h
    final_k<<<dim3(4096), blk, 0, stream>>>(gbuf, fz, h_in, (float*)d_out);
}

// Round 5
// 390.107 us; speedup vs baseline: 1.5523x; 1.0189x over previous
//
#include <hip/hip_runtime.h>
#include <hip/hip_bf16.h>

// ---------------- constants ----------------
constexpr int B_ = 8, C_ = 128, Hh = 64, Ww = 64, L_ = Hh * Ww;   // L = 4096
constexpr int CIN_ = 192, K_ = 4, Rr = 8, DFF_ = 512;
constexpr long SZ1 = (long)B_ * C_ * L_;                           // 4,194,304 floats
constexpr int CH_ = 32, NCH_ = L_ / CH_;                           // 128 chunks of 32
constexpr float EPSf = 1e-5f;

#define DEVI __device__ __forceinline__

using s16x4 = __attribute__((ext_vector_type(4))) short;
using s16x8 = __attribute__((ext_vector_type(8))) short;
using f32x4 = __attribute__((ext_vector_type(4))) float;

DEVI float sigm(float x) { return 1.f / (1.f + __expf(-x)); }
DEVI float geluf(float x) { return 0.5f * x * (1.f + erff(x * 0.70710678118654752f)); }
DEVI float siluf(float x) { return x * sigm(x); }
DEVI float softp(float z) { return (z > 15.f) ? z : __logf(1.f + __expf(z)); }

// float -> bf16 bits, round-to-nearest-even
DEVI unsigned short f2bf(float f) {
    unsigned u = __float_as_uint(f);
    u += 0x7fffu + ((u >> 16) & 1u);
    return (unsigned short)(u >> 16);
}

// transposed-plane ("scan order") address of position pos in a 64x64 plane
DEVI int tadr(int pos) { return ((pos & 63) << 6) | (pos >> 6); }

// ---------------- bf16 MFMA tiled GEMM ----------------
// C[M,N] (+)= W[M,K] @ X[K,N] (+bias) (sig) (gate-blend) ; X split/gelu on load.
template <bool ACC, bool BIAS, bool XGELU, bool SIG, bool GATE, bool SPLIT>
__global__ __launch_bounds__(256) void gemm_k(
    const float* __restrict__ W, const float* __restrict__ X1, long sX1,
    const float* __restrict__ X2, long sX2, int splitRow,
    const float* __restrict__ bias, float* __restrict__ Cp, long sC,
    int M, int N, int K)
{
    __shared__ unsigned short sA[128][40];   // [m][k] bf16, +8 pad
    __shared__ unsigned short sB[128][40];   // [n][k] bf16, +8 pad
    const int tid = threadIdx.x;
    const int bn = blockIdx.x, bm = blockIdx.y, bz = blockIdx.z;
    const float* X1b = X1 + (long)bz * sX1;
    const float* X2b = (SPLIT || GATE) ? (X2 + (long)bz * sX2) : nullptr;
    float* Cb = Cp + (long)bz * sC;
    const int n0 = bn * 128, m0 = bm * 128;

    const int l = tid & 63, w = tid >> 6;
    const int wm = w >> 1, wn = w & 1;             // 2x2 wave grid
    const int lr = l & 15, lk = (l >> 4) * 8;

    const int awrow = tid >> 1, awk = (tid & 1) * 16;
    const int bnb = tid & 31, bkb = tid >> 5;

    f32x4 acc[4][4];
#pragma unroll
    for (int i = 0; i < 4; i++)
#pragma unroll
        for (int j = 0; j < 4; j++) acc[i][j] = (f32x4)0.f;

    for (int k0 = 0; k0 < K; k0 += 32) {
        // ---- stage A (W tile) ----
        {
            const float* wp = W + (long)(m0 + awrow) * K + k0 + awk;
            float4 f0 = *(const float4*)(wp + 0);
            float4 f1 = *(const float4*)(wp + 4);
            float4 f2 = *(const float4*)(wp + 8);
            float4 f3 = *(const float4*)(wp + 12);
            s16x8 v0, v1;
            v0[0]=f2bf(f0.x); v0[1]=f2bf(f0.y); v0[2]=f2bf(f0.z); v0[3]=f2bf(f0.w);
            v0[4]=f2bf(f1.x); v0[5]=f2bf(f1.y); v0[6]=f2bf(f1.z); v0[7]=f2bf(f1.w);
            v1[0]=f2bf(f2.x); v1[1]=f2bf(f2.y); v1[2]=f2bf(f2.z); v1[3]=f2bf(f2.w);
            v1[4]=f2bf(f3.x); v1[5]=f2bf(f3.y); v1[6]=f2bf(f3.z); v1[7]=f2bf(f3.w);
            *(s16x8*)&sA[awrow][awk] = v0;
            *(s16x8*)&sA[awrow][awk + 8] = v1;
        }
        // ---- stage B (X tile, transposed to [n][k]) ----
        {
            const int krow = k0 + bkb * 4;
            const float* xp;
            if (SPLIT && krow >= splitRow)
                xp = X2b + (long)(krow - splitRow) * N + n0 + bnb * 4;
            else
                xp = X1b + (long)krow * N + n0 + bnb * 4;
            float4 r0 = *(const float4*)(xp + 0 * (long)N);
            float4 r1 = *(const float4*)(xp + 1 * (long)N);
            float4 r2 = *(const float4*)(xp + 2 * (long)N);
            float4 r3 = *(const float4*)(xp + 3 * (long)N);
            if (XGELU) {
                r0.x=geluf(r0.x); r0.y=geluf(r0.y); r0.z=geluf(r0.z); r0.w=geluf(r0.w);
                r1.x=geluf(r1.x); r1.y=geluf(r1.y); r1.z=geluf(r1.z); r1.w=geluf(r1.w);
                r2.x=geluf(r2.x); r2.y=geluf(r2.y); r2.z=geluf(r2.z); r2.w=geluf(r2.w);
                r3.x=geluf(r3.x); r3.y=geluf(r3.y); r3.z=geluf(r3.z); r3.w=geluf(r3.w);
            }
            const float* p0 = (const float*)&r0;
            const float* p1 = (const float*)&r1;
            const float* p2 = (const float*)&r2;
            const float* p3 = (const float*)&r3;
#pragma unroll
            for (int c = 0; c < 4; c++) {
                s16x4 v;
                v[0] = f2bf(p0[c]); v[1] = f2bf(p1[c]);
                v[2] = f2bf(p2[c]); v[3] = f2bf(p3[c]);
                *(s16x4*)&sB[bnb * 4 + c][bkb * 4] = v;
            }
        }
        __syncthreads();
        // ---- MFMA ----
        s16x8 af[4], bf[4];
#pragma unroll
        for (int mi = 0; mi < 4; mi++) af[mi] = *(const s16x8*)&sA[wm * 64 + mi * 16 + lr][lk];
#pragma unroll
        for (int ni = 0; ni < 4; ni++) bf[ni] = *(const s16x8*)&sB[wn * 64 + ni * 16 + lr][lk];
#pragma unroll
        for (int mi = 0; mi < 4; mi++)
#pragma unroll
            for (int ni = 0; ni < 4; ni++)
                acc[mi][ni] = __builtin_amdgcn_mfma_f32_16x16x32_bf16(af[mi], bf[ni], acc[mi][ni], 0, 0, 0);
        __syncthreads();
    }

    // ---- epilogue ----
#pragma unroll
    for (int mi = 0; mi < 4; mi++) {
#pragma unroll
        for (int r = 0; r < 4; r++) {
            const int row = m0 + wm * 64 + mi * 16 + (l >> 4) * 4 + r;
            const float bv = BIAS ? bias[row] : 0.f;
#pragma unroll
            for (int ni = 0; ni < 4; ni++) {
                const int col = n0 + wn * 64 + ni * 16 + lr;
                float* cp = Cb + (long)row * N + col;
                float v = acc[mi][ni][r] + bv;
                if (ACC) v += *cp;
                if (SIG) v = sigm(v);
                if (GATE) {
                    v = sigm(v);
                    float zv = X1b[(long)row * N + col];
                    float hv = X2b[(long)row * N + col];
                    v = hv + v * (zv - hv);
                }
                *cp = v;
            }
        }
    }
}

// ---------------- channel LayerNorm (channel_first) ----------------
__global__ __launch_bounds__(256) void ln_cf_k(const float* __restrict__ in,
                                               const float* __restrict__ g,
                                               const float* __restrict__ bta,
                                               float* __restrict__ out)
{
    __shared__ float s1[4][64], s2[4][64];
    const int tid = threadIdx.x;
    const int p = tid & 63, q = tid >> 6;
    const long posg = (long)blockIdx.x * 64 + p;
    const int b = (int)(posg / L_);
    const int pp = (int)(posg % L_);
    const float* base = in + ((long)b * C_ + q * 32) * L_ + pp;
    float v[32];
    float s = 0.f, sq = 0.f;
#pragma unroll
    for (int i = 0; i < 32; i++) {
        float t = base[(long)i * L_];
        v[i] = t; s += t; sq += t * t;
    }
    s1[q][p] = s; s2[q][p] = sq;
    __syncthreads();
    float ts = s1[0][p] + s1[1][p] + s1[2][p] + s1[3][p];
    float tq = s2[0][p] + s2[1][p] + s2[2][p] + s2[3][p];
    float mu = ts * (1.f / 128.f);
    float var = tq * (1.f / 128.f) - mu * mu;
    float rs = rsqrtf(var + EPSf);
    float* ob = out + ((long)b * C_ + q * 32) * L_ + pp;
#pragma unroll
    for (int i = 0; i < 32; i++) {
        int c = q * 32 + i;
        ob[(long)i * L_] = (v[i] - mu) * rs * g[c] + bta[c];
    }
}

// ---------------- fused depthwise 3x3 + SiLU, writes u AND u^T ----------------
__global__ __launch_bounds__(256) void dwconvT_k(const float* __restrict__ in,
                                                 const float* __restrict__ wts,
                                                 const float* __restrict__ bias,
                                                 float* __restrict__ uo,
                                                 float* __restrict__ uTo)
{
    __shared__ float t[64][65];
    const long plane = blockIdx.x;
    const int c = (int)(plane & 127);
    const int tid = threadIdx.x;
    const float* src = in + plane * (long)L_;
#pragma unroll
    for (int ii = 0; ii < 16; ii++) {
        int idx = tid + ii * 256;
        t[idx >> 6][idx & 63] = src[idx];
    }
    float kw[9];
#pragma unroll
    for (int q = 0; q < 9; q++) kw[q] = wts[c * 9 + q];
    const float bc = bias[c];
    __syncthreads();
    float r[16];
#pragma unroll
    for (int ii = 0; ii < 16; ii++) {
        int idx = tid + ii * 256;
        int h = idx >> 6, w2 = idx & 63;
        float acc = bc;
#pragma unroll
        for (int dh = -1; dh <= 1; dh++) {
            int hh = h + dh;
            if ((unsigned)hh >= 64u) continue;
#pragma unroll
            for (int dw = -1; dw <= 1; dw++) {
                int ww2 = w2 + dw;
                if ((unsigned)ww2 >= 64u) continue;
                acc += t[hh][ww2] * kw[(dh + 1) * 3 + (dw + 1)];
            }
        }
        r[ii] = siluf(acc);
    }
    __syncthreads();
    float* ud = uo + plane * (long)L_;
#pragma unroll
    for (int ii = 0; ii < 16; ii++) {
        int idx = tid + ii * 256;
        t[idx >> 6][idx & 63] = r[ii];
        ud[idx] = r[ii];
    }
    __syncthreads();
    float* utd = uTo + plane * (long)L_;
#pragma unroll
    for (int ii = 0; ii < 16; ii++) {
        int idx = tid + ii * 256;
        utd[idx] = t[idx & 63][idx >> 6];
    }
}

// ---------------- per-plane 64x64 transpose-add ----------------
template <bool ADD>
__global__ __launch_bounds__(256) void transp_k(const float* __restrict__ src,
                                                float* __restrict__ dst)
{
    __shared__ float t[64][65];
    const long plane = blockIdx.x;
    const float* s = src + plane * (long)L_;
    float* d = dst + plane * (long)L_;
    const int tid = threadIdx.x;
#pragma unroll
    for (int i = 0; i < 16; i++) {
        int idx = tid + i * 256;
        t[idx >> 6][idx & 63] = s[idx];
    }
    __syncthreads();
#pragma unroll
    for (int i = 0; i < 16; i++) {
        int idx = tid + i * 256;
        int r = idx >> 6, cc = idx & 63;
        float val = t[cc][r];
        if (ADD) d[idx] += val; else d[idx] = val;
    }
}

// ---------------- x_dbl projection (stored in SCAN ORDER) ----------------
__global__ __launch_bounds__(256) void xdbl_k(const float* __restrict__ u,
                                              const float* __restrict__ uT,
                                              const float* __restrict__ xw,
                                              float* __restrict__ out)
{
    __shared__ float wsm[16][132];
    const int k = blockIdx.y, b = blockIdx.z;
    const int tid = threadIdx.x;
#pragma unroll
    for (int i = 0; i < 8; i++) {
        int idx = tid * 8 + i;
        wsm[idx >> 7][idx & 127] = xw[k * 2048 + idx];
    }
    __syncthreads();
    const int dg = (tid & 3) * 4;
    const int lo = tid >> 2;
    const int l = blockIdx.x * 64 + lo;
    const int pos = (k >= 2) ? (L_ - 1 - l) : l;
    const float* usrc = ((k & 1) ? uT : u) + (long)b * C_ * L_ + pos;
    float a0 = 0.f, a1 = 0.f, a2 = 0.f, a3 = 0.f;
#pragma unroll 4
    for (int c = 0; c < C_; c++) {
        float uc = usrc[(long)c * L_];
        a0 += wsm[dg + 0][c] * uc;
        a1 += wsm[dg + 1][c] * uc;
        a2 += wsm[dg + 2][c] * uc;
        a3 += wsm[dg + 3][c] * uc;
    }
    float4 o = make_float4(a0, a1, a2, a3);
    const long s = tadr(l);
    *(float4*)(out + (((long)(b * K_ + k) * L_ + s) << 4) + dg) = o;
}

// ---------------- scan phase 1 (CH=32, 128 chunks/chain) ----------------
__global__ __launch_bounds__(256) void scan_ph1_k(const float* __restrict__ xdbl,
                                                  const float* __restrict__ u,
                                                  const float* __restrict__ uT,
                                                  const float* __restrict__ dtw,
                                                  const float* __restrict__ dtb,
                                                  const float* __restrict__ alogs,
                                                  float* __restrict__ st)
{
    const long t = (long)blockIdx.x * 256 + threadIdx.x;   // B*K*C*128 = 524288
    const int j = (int)(t & 127);                           // chunk index
    const long chain = t >> 7;                              // 4096
    const int c = (int)(chain & 127);
    const int bk = (int)(chain >> 7);
    const int k = bk & 3, b = bk >> 2;
    const float4* xd = (const float4*)(xdbl + (((long)(b * K_ + k) * L_) << 4));
    const float* usrc = ((k & 1) ? u : uT) + ((long)b * C_ + c) * L_;
    const bool rev = (k >= 2);
    float dw[8];
#pragma unroll
    for (int r = 0; r < 8; r++) dw[r] = dtw[((k * C_ + c) << 3) + r];
    const float db = dtb[k * C_ + c];
    float An[4];
#pragma unroll
    for (int n = 0; n < 4; n++) An[n] = -__expf(alogs[((k * C_ + c) << 2) + n]);
    float P0 = 1.f, P1 = 1.f, P2 = 1.f, P3 = 1.f;
    float S0 = 0.f, S1 = 0.f, S2 = 0.f, S3 = 0.f;
    for (int i = 0; i < CH_; i++) {
        int l = (j << 5) | i;
        int sidx = tadr(l);
        int pos = rev ? (L_ - 1 - l) : l;
        float4 d0 = xd[sidx * 4 + 0];
        float4 d1 = xd[sidx * 4 + 1];
        float4 bs = xd[sidx * 4 + 2];
        float uv = usrc[tadr(pos)];
        float z = db + d0.x * dw[0] + d0.y * dw[1] + d0.z * dw[2] + d0.w * dw[3]
                     + d1.x * dw[4] + d1.y * dw[5] + d1.z * dw[6] + d1.w * dw[7];
        float dl = softp(z);
        float du = dl * uv;
        float e;
        e = __expf(dl * An[0]); S0 = e * S0 + du * bs.x; P0 *= e;
        e = __expf(dl * An[1]); S1 = e * S1 + du * bs.y; P1 *= e;
        e = __expf(dl * An[2]); S2 = e * S2 + du * bs.z; P2 *= e;
        e = __expf(dl * An[3]); S3 = e * S3 + du * bs.w; P3 *= e;
    }
    float* o = st + (chain << 10) + (j << 3);
    *(float4*)o = make_float4(P0, P1, P2, P3);
    *(float4*)(o + 4) = make_float4(S0, S1, S2, S3);
}

// ---------------- scan mid: wave scans 128 chunks (2 per lane) ----------------
__global__ __launch_bounds__(256) void scan_mid_k(float* __restrict__ st)
{
    const long t = (long)blockIdx.x * 256 + threadIdx.x;   // 4096 chains * 64 lanes
    const long chain = t >> 6;
    const int ln = (int)(t & 63);
    float* base = st + (chain << 10) + (ln << 4);
    float4 Pa = *(float4*)(base + 0);
    float4 Sa = *(float4*)(base + 4);
    float4 Pb = *(float4*)(base + 8);
    float4 Sb = *(float4*)(base + 12);
    // combine chunk pair (2ln then 2ln+1)
    float4 P, S;
    P.x = Pb.x * Pa.x; P.y = Pb.y * Pa.y; P.z = Pb.z * Pa.z; P.w = Pb.w * Pa.w;
    S.x = Sb.x + Pb.x * Sa.x; S.y = Sb.y + Pb.y * Sa.y;
    S.z = Sb.z + Pb.z * Sa.z; S.w = Sb.w + Pb.w * Sa.w;
#pragma unroll
    for (int d = 1; d < 64; d <<= 1) {
        float4 Pu, Su;
        Pu.x = __shfl_up(P.x, d, 64); Pu.y = __shfl_up(P.y, d, 64);
        Pu.z = __shfl_up(P.z, d, 64); Pu.w = __shfl_up(P.w, d, 64);
        Su.x = __shfl_up(S.x, d, 64); Su.y = __shfl_up(S.y, d, 64);
        Su.z = __shfl_up(S.z, d, 64); Su.w = __shfl_up(S.w, d, 64);
        if (ln >= d) {
            S.x += P.x * Su.x; S.y += P.y * Su.y;
            S.z += P.z * Su.z; S.w += P.w * Su.w;
            P.x *= Pu.x; P.y *= Pu.y; P.z *= Pu.z; P.w *= Pu.w;
        }
    }
    float4 E;
    E.x = __shfl_up(S.x, 1, 64); E.y = __shfl_up(S.y, 1, 64);
    E.z = __shfl_up(S.z, 1, 64); E.w = __shfl_up(S.w, 1, 64);
    if (ln == 0) { E.x = 0.f; E.y = 0.f; E.z = 0.f; E.w = 0.f; }
    float4 E1;
    E1.x = Sa.x + Pa.x * E.x; E1.y = Sa.y + Pa.y * E.y;
    E1.z = Sa.z + Pa.z * E.z; E1.w = Sa.w + Pa.w * E.w;
    *(float4*)(base + 4)  = E;    // entering state of chunk 2ln
    *(float4*)(base + 12) = E1;   // entering state of chunk 2ln+1
}

// ---------------- fused bidirectional scan phase 2 ----------------
// thread: fwd chunk j of chain (b,c,kh) + bwd chunk 127-j of chain (b,c,kh+2);
// both cover output positions 32j..32j+31; accumulate in yrow, single write.
__global__ __launch_bounds__(256) void scan_ph2f_k(const float* __restrict__ xdbl,
                                                   const float* __restrict__ u,
                                                   const float* __restrict__ uT,
                                                   const float* __restrict__ dtw,
                                                   const float* __restrict__ dtb,
                                                   const float* __restrict__ alogs,
                                                   const float* __restrict__ Dsp,
                                                   const float* __restrict__ st,
                                                   float* __restrict__ Y0,
                                                   float* __restrict__ Yt)
{
    const long t = (long)blockIdx.x * 256 + threadIdx.x;   // B*C*2*128 = 262144
    const int j = (int)(t & 127);
    const long bck = t >> 7;
    const int c  = (int)(bck & 127);
    const int kh = (int)((bck >> 7) & 1);
    const int b  = (int)(bck >> 8);
    const int kf = kh, kb = kh + 2;
    const int jb = 127 - j;
    const long chf = (long)(b * K_ + kf) * C_ + c;
    const long chb = (long)(b * K_ + kb) * C_ + c;
    const float4* xf = (const float4*)(xdbl + (((long)(b * K_ + kf) * L_) << 4));
    const float4* xb = (const float4*)(xdbl + (((long)(b * K_ + kb) * L_) << 4));
    const float* usrc = ((kh & 1) ? u : uT) + ((long)b * C_ + c) * L_;
    float* ydst = ((kh & 1) ? Yt : Y0) + ((long)b * C_ + c) * L_;

    float dwf[8], dwb[8];
#pragma unroll
    for (int r = 0; r < 8; r++) dwf[r] = dtw[((kf * C_ + c) << 3) + r];
#pragma unroll
    for (int r = 0; r < 8; r++) dwb[r] = dtw[((kb * C_ + c) << 3) + r];
    const float dbf = dtb[kf * C_ + c], dbb = dtb[kb * C_ + c];
    float Anf[4], Anb[4];
#pragma unroll
    for (int n = 0; n < 4; n++) Anf[n] = -__expf(alogs[((kf * C_ + c) << 2) + n]);
#pragma unroll
    for (int n = 0; n < 4; n++) Anb[n] = -__expf(alogs[((kb * C_ + c) << 2) + n]);
    const float Dcf = Dsp[kf * C_ + c], Dcb = Dsp[kb * C_ + c];

    float yrow[32];
    // ---- forward pass (k=kh, chunk j, positions 32j+i) ----
    {
        float4 H = *(const float4*)(st + (chf << 10) + (j << 3) + 4);
        float h0 = H.x, h1 = H.y, h2 = H.z, h3 = H.w;
#pragma unroll
        for (int i = 0; i < 32; i++) {
            const int l = (j << 5) | i;
            const int sidx = tadr(l);                 // == tadr(pos), pos = l
            float4 d0 = xf[sidx * 4 + 0];
            float4 d1 = xf[sidx * 4 + 1];
            float4 bs = xf[sidx * 4 + 2];
            float4 cs = xf[sidx * 4 + 3];
            float uv = usrc[sidx];
            float z = dbf + d0.x*dwf[0] + d0.y*dwf[1] + d0.z*dwf[2] + d0.w*dwf[3]
                          + d1.x*dwf[4] + d1.y*dwf[5] + d1.z*dwf[6] + d1.w*dwf[7];
            float dl = softp(z);
            float du = dl * uv;
            float e;
            e = __expf(dl * Anf[0]); h0 = e * h0 + du * bs.x;
            e = __expf(dl * Anf[1]); h1 = e * h1 + du * bs.y;
            e = __expf(dl * Anf[2]); h2 = e * h2 + du * bs.z;
            e = __expf(dl * Anf[3]); h3 = e * h3 + du * bs.w;
            yrow[i] = h0 * cs.x + h1 * cs.y + h2 * cs.z + h3 * cs.w + Dcf * uv;
        }
    }
    // ---- backward pass (k=kh+2, chunk 127-j, positions 32j+31-i) ----
    {
        float4 H = *(const float4*)(st + (chb << 10) + (jb << 3) + 4);
        float h0 = H.x, h1 = H.y, h2 = H.z, h3 = H.w;
#pragma unroll
        for (int i = 0; i < 32; i++) {
            const int lb = (jb << 5) | i;             // scan index in bwd chain
            const int sidx = tadr(lb);
            const int pos = L_ - 1 - lb;              // = 32j + (31-i)
            float4 d0 = xb[sidx * 4 + 0];
            float4 d1 = xb[sidx * 4 + 1];
            float4 bs = xb[sidx * 4 + 2];
            float4 cs = xb[sidx * 4 + 3];
            float uv = usrc[tadr(pos)];
            float z = dbb + d0.x*dwb[0] + d0.y*dwb[1] + d0.z*dwb[2] + d0.w*dwb[3]
                          + d1.x*dwb[4] + d1.y*dwb[5] + d1.z*dwb[6] + d1.w*dwb[7];
            float dl = softp(z);
            float du = dl * uv;
            float e;
            e = __expf(dl * Anb[0]); h0 = e * h0 + du * bs.x;
            e = __expf(dl * Anb[1]); h1 = e * h1 + du * bs.y;
            e = __expf(dl * Anb[2]); h2 = e * h2 + du * bs.z;
            e = __expf(dl * Anb[3]); h3 = e * h3 + du * bs.w;
            yrow[31 - i] += h0 * cs.x + h1 * cs.y + h2 * cs.z + h3 * cs.w + Dcb * uv;
        }
    }
    // ---- single coalesced write ----
#pragma unroll
    for (int i = 0; i < 32; i++) {
        const int pos = (j << 5) | i;
        ydst[tadr(pos)] = yrow[i];
    }
}

// ---------------- launch ----------------
extern "C" void kernel_launch(void* const* d_in, const int* in_sizes, int n_in,
                              void* d_out, int out_size, void* d_ws, size_t ws_size,
                              hipStream_t stream)
{
    const float* h_in      = (const float*)d_in[0];
    const float* x_in      = (const float*)d_in[4];
    const float* in_proj_w = (const float*)d_in[5];
    const float* in_proj_b = (const float*)d_in[6];
    const float* ln1_g     = (const float*)d_in[7];
    const float* ln1_b     = (const float*)d_in[8];
    const float* ssm_in_w  = (const float*)d_in[9];
    const float* conv_w    = (const float*)d_in[10];
    const float* conv_b    = (const float*)d_in[11];
    const float* x_proj_w  = (const float*)d_in[12];
    const float* dt_w      = (const float*)d_in[13];
    const float* dt_b      = (const float*)d_in[14];
    const float* A_logs    = (const float*)d_in[15];
    const float* Dsp       = (const float*)d_in[16];
    const float* outnorm_g = (const float*)d_in[17];
    const float* outnorm_b = (const float*)d_in[18];
    const float* out_proj_w= (const float*)d_in[19];
    const float* ln2_g     = (const float*)d_in[20];
    const float* ln2_b     = (const float*)d_in[21];
    const float* fc1_w     = (const float*)d_in[22];
    const float* fc1_b     = (const float*)d_in[23];
    const float* fc2_w     = (const float*)d_in[24];
    const float* fc2_b     = (const float*)d_in[25];
    const float* gate_w    = (const float*)d_in[26];
    const float* gate_b    = (const float*)d_in[27];

    float* ws   = (float*)d_ws;
    float* fz   = ws;              // feat -> z (in place)
    float* ubuf = ws + SZ1;        // u ; MLP hidden overlays
    float* tbuf = ws + 2 * SZ1;    // u0 -> u_T -> y_norm
    float* ybuf = ws + 3 * SZ1;    // ln1out -> TY0 -> ln2out
    float* xdbl = ws + 4 * SZ1;    // [B,K,L(scan order),16] = 2,097,152 floats
    float* stbf = ws + 4 * SZ1 + 2097152;  // 4096 chains * 128 chunks * 8 = 4,194,304
    float* mbuf = ubuf;
    float* gbuf = (float*)d_out;   // TYt -> merged y -> final out

    const dim3 blk(256);
    const long sBC = (long)C_ * L_;
    const long sX  = (long)CIN_ * L_;
    const long sM  = (long)DFF_ * L_;

    // 1) feat = in_proj @ concat(h, x) + b
    gemm_k<false, true, false, false, false, true><<<dim3(32, 1, 8), blk, 0, stream>>>(
        in_proj_w, h_in, sBC, x_in, sX, 128, in_proj_b, fz, sBC, 128, L_, 320);
    // 2) ln1(feat) -> ybuf
    ln_cf_k<<<dim3(512), blk, 0, stream>>>(fz, ln1_g, ln1_b, ybuf);
    // 3) u0 = ssm_in @ ln1 -> tbuf
    gemm_k<false, false, false, false, false, false><<<dim3(32, 1, 8), blk, 0, stream>>>(
        ssm_in_w, ybuf, sBC, nullptr, 0, 1 << 30, nullptr, tbuf, sBC, 128, L_, 128);
    // 4+5) u = silu(dwconv(u0)+b) -> ubuf, u^T -> tbuf (fused; tbuf read before overwrite? NO:
    //      dwconvT reads tbuf fully into LDS before writing uT -> but different planes race!)
    //      -> write uT into a disjoint region: reuse ybuf (ln1out is dead after step 3).
    dwconvT_k<<<dim3(1024), blk, 0, stream>>>(tbuf, conv_w, conv_b, ubuf, ybuf);
    // 6) x_dbl (scan-order layout); uT now lives in ybuf
    xdbl_k<<<dim3(64, 4, 8), blk, 0, stream>>>(ubuf, ybuf, x_proj_w, xdbl);
    // 7) scan phase 1
    scan_ph1_k<<<dim3(2048), blk, 0, stream>>>(xdbl, ubuf, ybuf, dt_w, dt_b, A_logs, stbf);
    // 8) chunk-boundary chaining
    scan_mid_k<<<dim3(1024), blk, 0, stream>>>(stbf);
    // 9) fused bidirectional phase 2: TY0 -> tbuf, TYt -> gbuf
    scan_ph2f_k<<<dim3(1024), blk, 0, stream>>>(xdbl, ubuf, ybuf, dt_w, dt_b,
                                                A_logs, Dsp, stbf, tbuf, gbuf);
    // 10) merged y: gbuf += transpose(tbuf)
    transp_k<true><<<dim3(1024), blk, 0, stream>>>(tbuf, gbuf);
    // 11) outnorm(y) -> tbuf
    ln_cf_k<<<dim3(512), blk, 0, stream>>>(gbuf, outnorm_g, outnorm_b, tbuf);
    // 12) z = feat + out_proj @ y_norm   (ACC into fz)
    gemm_k<true, false, false, false, false, false><<<dim3(32, 1, 8), blk, 0, stream>>>(
        out_proj_w, tbuf, sBC, nullptr, 0, 1 << 30, nullptr, fz, sBC, 128, L_, 128);
    // 13) ln2(z) -> ybuf
    ln_cf_k<<<dim3(512), blk, 0, stream>>>(fz, ln2_g, ln2_b, ybuf);
    // 14-17) MLP in two 4-batch halves
    for (int half = 0; half < 2; half++) {
        long o = (long)half * 4 * sBC;
        gemm_k<false, true, false, false, false, false><<<dim3(32, 4, 4), blk, 0, stream>>>(
            fc1_w, ybuf + o, sBC, nullptr, 0, 1 << 30, fc1_b, mbuf, sM, 512, L_, 128);
        gemm_k<true, true, true, false, false, false><<<dim3(32, 1, 4), blk, 0, stream>>>(
            fc2_w, mbuf, sM, nullptr, 0, 1 << 30, fc2_b, fz + o, sBC, 128, L_, 512);
    }
    // 18) out = g*z + (1-g)*h, g = sigmoid(gate@z+b)  (fused epilogue, writes d_out)
    gemm_k<false, true, false, false, true, false><<<dim3(32, 1, 8), blk, 0, stream>>>(
        gate_w, fz, sBC, h_in, sBC, 1 << 30, gate_b, (float*)d_out, sBC, 128, L_, 128);
}